// Round 1
// baseline (207.929 us; speedup 1.0000x reference)
//
#include <hip/hip_runtime.h>
#include <math.h>

#define ALPHA_LEAKY 0.2f
#define EPS_F 1e-10f

typedef __attribute__((ext_vector_type(8))) short short8;   // 8 bf16 (4 VGPRs)
typedef __attribute__((ext_vector_type(4))) float f32x4;    // MFMA C/D frag

__device__ __forceinline__ unsigned short bf16_rne(float f) {
    unsigned u = __float_as_uint(f);
    u += 0x7FFFu + ((u >> 16) & 1u);
    return (unsigned short)(u >> 16);
}

// MFMA GEMM + fused scores + fused degree count.
// One wave per 16-row stripe; W-frags built in-kernel from fp32 W (L2-cached,
// one-time per wave) -- k_prep launch eliminated. After stripe work each
// block counts degrees for its edge chunk (global atomics, random over N
// counters -> negligible contention).
// C/D map: col = lane&15 (ml), row = (lane>>4)*4 + reg.
__global__ __launch_bounds__(256) void k_gemm(
    const float* __restrict__ X, const float* __restrict__ W,
    const float* __restrict__ a, unsigned short* __restrict__ hb,
    float* __restrict__ s_src, float* __restrict__ s_tgt,
    const int* __restrict__ ei, int* __restrict__ deg,
    int n, int nstripes, int E, int epb) {
    const int lane = threadIdx.x & 63;
    const int ml = lane & 15, g = lane >> 4;

    // Build B-frags for W directly from fp32 (identical layout to old k_prep):
    // frag(nt,kt): nn = nt*16 + (lane&15), k = kt*32 + (lane>>4)*8, 8 elems.
    short8 bfr[4][4];
    #pragma unroll
    for (int nt = 0; nt < 4; ++nt)
        #pragma unroll
        for (int kt = 0; kt < 4; ++kt) {
            const float* wr = W + (nt * 16 + ml) * 128 + kt * 32 + g * 8;
            float4 w0 = *(const float4*)wr;
            float4 w1 = *(const float4*)(wr + 4);
            short8 bf;
            bf[0] = (short)bf16_rne(w0.x); bf[1] = (short)bf16_rne(w0.y);
            bf[2] = (short)bf16_rne(w0.z); bf[3] = (short)bf16_rne(w0.w);
            bf[4] = (short)bf16_rne(w1.x); bf[5] = (short)bf16_rne(w1.y);
            bf[6] = (short)bf16_rne(w1.z); bf[7] = (short)bf16_rne(w1.w);
            bfr[nt][kt] = bf;
        }
    float as[4], at[4];
    #pragma unroll
    for (int nt = 0; nt < 4; ++nt) {
        as[nt] = a[nt * 16 + ml];
        at[nt] = a[64 + nt * 16 + ml];
    }

    for (int stripe = blockIdx.x * 4 + (threadIdx.x >> 6); stripe < nstripes;
         stripe += gridDim.x * 4) {
        const int row0 = stripe * 16;
        const int rrow = min(row0 + ml, n - 1);
        const float* xr = X + (size_t)rrow * 128;
        f32x4 acc[4] = {{0.f,0.f,0.f,0.f},{0.f,0.f,0.f,0.f},
                        {0.f,0.f,0.f,0.f},{0.f,0.f,0.f,0.f}};
        #pragma unroll
        for (int kt = 0; kt < 4; ++kt) {
            float4 x0 = *(const float4*)(xr + kt * 32 + g * 8);
            float4 x1 = *(const float4*)(xr + kt * 32 + g * 8 + 4);
            short8 af;
            af[0] = (short)bf16_rne(x0.x); af[1] = (short)bf16_rne(x0.y);
            af[2] = (short)bf16_rne(x0.z); af[3] = (short)bf16_rne(x0.w);
            af[4] = (short)bf16_rne(x1.x); af[5] = (short)bf16_rne(x1.y);
            af[6] = (short)bf16_rne(x1.z); af[7] = (short)bf16_rne(x1.w);
            #pragma unroll
            for (int nt = 0; nt < 4; ++nt)
                acc[nt] = __builtin_amdgcn_mfma_f32_16x16x32_bf16(
                    af, bfr[nt][kt], acc[nt], 0, 0, 0);
        }
        #pragma unroll
        for (int reg = 0; reg < 4; ++reg) {
            int row = row0 + g * 4 + reg;
            float p = acc[0][reg] * as[0] + acc[1][reg] * as[1] +
                      acc[2][reg] * as[2] + acc[3][reg] * as[3];
            float q = acc[0][reg] * at[0] + acc[1][reg] * at[1] +
                      acc[2][reg] * at[2] + acc[3][reg] * at[3];
            #pragma unroll
            for (int off = 1; off < 16; off <<= 1) {
                p += __shfl_xor(p, off, 64);
                q += __shfl_xor(q, off, 64);
            }
            if (ml == 0 && row < n) { s_src[row] = p; s_tgt[row] = q; }
        }
        #pragma unroll
        for (int nt = 0; nt < 4; ++nt)
            #pragma unroll
            for (int reg = 0; reg < 4; ++reg) {
                int row = row0 + g * 4 + reg;
                if (row < n)
                    hb[(size_t)row * 64 + nt * 16 + ml] = bf16_rne(acc[nt][reg]);
            }
    }

    // fused degree count over this block's edge chunk
    {
        const int e0 = blockIdx.x * epb;
        const int e1 = min(e0 + epb, E);
        for (int e = e0 + (int)threadIdx.x; e < e1; e += 256)
            atomicAdd(&deg[ei[E + e]], 1);
    }
}

// Region allocation: per-block scan of 256 degrees + one global atomicAdd
// per block on a single counter (196 same-address atomics total -> cheap).
// Regions land in arbitrary node order -- k_node does not care.
__global__ __launch_bounds__(256) void k_alloc(
    const int* __restrict__ deg, int* __restrict__ cur,
    int* __restrict__ cnt, int n) {
    __shared__ int wsum[4];
    __shared__ int bbase;
    const int t = threadIdx.x, lane = t & 63, w = t >> 6;
    const int node = blockIdx.x * 256 + t;
    int v = (node < n) ? deg[node] : 0;
    int pre = v;
    #pragma unroll
    for (int off = 1; off < 64; off <<= 1) {
        int x = __shfl_up(pre, off, 64);
        if (lane >= off) pre += x;
    }
    if (lane == 63) wsum[w] = pre;
    __syncthreads();
    if (t == 0) {
        int tot = wsum[0] + wsum[1] + wsum[2] + wsum[3];
        bbase = atomicAdd(cnt, tot);
    }
    __syncthreads();
    int wb = bbase;
    for (int k = 0; k < w; ++k) wb += wsum[k];
    if (node < n) cur[node] = wb + pre - v;    // exclusive start of region
}

// Place edges: slot = cursor++ of target node. After this kernel,
// cur[node] == base + deg, so base is recoverable as cur - deg.
__global__ __launch_bounds__(256) void k_fill(
    const int* __restrict__ ei, int* __restrict__ cur,
    int* __restrict__ csr_src, int E) {
    const int stride = gridDim.x * 256;
    for (int e = blockIdx.x * 256 + (int)threadIdx.x; e < E; e += stride) {
        int s  = ei[e];
        int tt = ei[E + e];
        int slot = atomicAdd(&cur[tt], 1);
        csr_src[slot] = s;
    }
}

// per-node softmax + aggregation + ELU (one wave per node; lane = (g,r);
// 8 edges per step, each 8-lane group reads one 128 B bf16 row as uint4).
__device__ __forceinline__ void accum8(float acc[8], uint4 hv, float w) {
    unsigned u[4] = {hv.x, hv.y, hv.z, hv.w};
    #pragma unroll
    for (int i = 0; i < 4; ++i) {
        float lo = __uint_as_float(u[i] << 16);
        float hi = __uint_as_float(u[i] & 0xFFFF0000u);
        acc[2 * i]     = fmaf(w, lo, acc[2 * i]);
        acc[2 * i + 1] = fmaf(w, hi, acc[2 * i + 1]);
    }
}

__global__ __launch_bounds__(256) void k_node(
    const int* __restrict__ deg, const int* __restrict__ cur,
    const int* __restrict__ csr_src, const float* __restrict__ s_src,
    const float* __restrict__ s_tgt, const unsigned short* __restrict__ hb,
    float* __restrict__ out, int n) {
    const int lane = threadIdx.x & 63;
    const int node = blockIdx.x * 4 + (threadIdx.x >> 6);
    if (node >= n) return;
    const int d = deg[node];
    const int b = cur[node] - d;               // cur is base+deg after k_fill
    const float st = s_tgt[node];
    const int g = lane >> 3, r = lane & 7;
    float acc[8] = {0.f, 0.f, 0.f, 0.f, 0.f, 0.f, 0.f, 0.f};

    if (d <= 64) {
        int src_l = 0; float w_l = 0.f, v = -INFINITY;
        if (lane < d) {
            src_l = csr_src[b + lane];
            float x = s_src[src_l] + st;
            v = (x > 0.f) ? x : ALPHA_LEAKY * x;
        }
        float m = v;
        #pragma unroll
        for (int off = 32; off > 0; off >>= 1) m = fmaxf(m, __shfl_xor(m, off, 64));
        float ex = (lane < d) ? expf(v - m) : 0.f;
        float sum = ex;
        #pragma unroll
        for (int off = 32; off > 0; off >>= 1) sum += __shfl_xor(sum, off, 64);
        w_l = ex * (1.f / (sum + EPS_F));
        for (int k = 0; k < d; k += 8) {
            int ke = k + g;
            int s   = __shfl(src_l, ke, 64);
            float w = __shfl(w_l,  ke, 64);
            uint4 hv = ((const uint4*)(hb + (size_t)s * 64))[r];
            accum8(acc, hv, w);
        }
    } else {
        float m = -INFINITY;
        for (int c = lane; c < d; c += 64) {
            float x = s_src[csr_src[b + c]] + st;
            x = (x > 0.f) ? x : ALPHA_LEAKY * x;
            m = fmaxf(m, x);
        }
        #pragma unroll
        for (int off = 32; off > 0; off >>= 1) m = fmaxf(m, __shfl_xor(m, off, 64));
        float sum = 0.f;
        for (int c = lane; c < d; c += 64) {
            float x = s_src[csr_src[b + c]] + st;
            x = (x > 0.f) ? x : ALPHA_LEAKY * x;
            sum += expf(x - m);
        }
        #pragma unroll
        for (int off = 32; off > 0; off >>= 1) sum += __shfl_xor(sum, off, 64);
        float inv = 1.f / (sum + EPS_F);
        for (int c0 = 0; c0 < d; c0 += 64) {
            int j = c0 + lane;
            int src_l = 0; float w_l = 0.f;
            if (j < d) {
                src_l = csr_src[b + j];
                float x = s_src[src_l] + st;
                x = (x > 0.f) ? x : ALPHA_LEAKY * x;
                w_l = expf(x - m) * inv;
            }
            int lim = min(64, d - c0);
            for (int k = 0; k < lim; k += 8) {
                int ke = k + g;
                int s   = __shfl(src_l, ke, 64);
                float w = __shfl(w_l,  ke, 64);
                uint4 hv = ((const uint4*)(hb + (size_t)s * 64))[r];
                accum8(acc, hv, w);
            }
        }
    }

    #pragma unroll
    for (int off = 8; off <= 32; off <<= 1) {
        #pragma unroll
        for (int j = 0; j < 8; ++j) acc[j] += __shfl_xor(acc[j], off, 64);
    }
    if (g == 0) {
        float4 o0, o1;
        o0.x = acc[0] > 0.f ? acc[0] : expf(acc[0]) - 1.f;
        o0.y = acc[1] > 0.f ? acc[1] : expf(acc[1]) - 1.f;
        o0.z = acc[2] > 0.f ? acc[2] : expf(acc[2]) - 1.f;
        o0.w = acc[3] > 0.f ? acc[3] : expf(acc[3]) - 1.f;
        o1.x = acc[4] > 0.f ? acc[4] : expf(acc[4]) - 1.f;
        o1.y = acc[5] > 0.f ? acc[5] : expf(acc[5]) - 1.f;
        o1.z = acc[6] > 0.f ? acc[6] : expf(acc[6]) - 1.f;
        o1.w = acc[7] > 0.f ? acc[7] : expf(acc[7]) - 1.f;
        float4* o4 = (float4*)out + (size_t)node * 16;
        o4[r * 2]     = o0;
        o4[r * 2 + 1] = o1;
    }
}

extern "C" void kernel_launch(void* const* d_in, const int* in_sizes, int n_in,
                              void* d_out, int out_size, void* d_ws, size_t ws_size,
                              hipStream_t stream) {
    const float* X  = (const float*)d_in[0];   // [N,128]
    const int*   ei = (const int*)d_in[1];     // [2,E]
    const float* W  = (const float*)d_in[2];   // [64,128]
    const float* a  = (const float*)d_in[3];   // [1,128]
    float* out = (float*)d_out;                // [N,64]

    const int N = in_sizes[0] / 128;
    const int E = in_sizes[1] / 2;

    char* p = (char*)d_ws;
    unsigned short* hb = (unsigned short*)p; p += (size_t)N * 64 * sizeof(unsigned short);
    float* s_src  = (float*)p;  p += (size_t)N * sizeof(float);
    float* s_tgt  = (float*)p;  p += (size_t)N * sizeof(float);
    int*   deg    = (int*)p;    p += (size_t)N * sizeof(int);
    int*   cnt    = (int*)p;    p += 4 * sizeof(int);        // adjacent to deg for one memset
    int*   cur    = (int*)p;    p += (size_t)N * sizeof(int);
    int*   csr_src= (int*)p;

    const int nstripes = (N + 15) / 16;
    const int gblk = (nstripes + 3) / 4;                     // k_gemm blocks
    const int epb  = (E + gblk - 1) / gblk;                  // edges per gemm block

    hipMemsetAsync(deg, 0, (size_t)(N + 4) * sizeof(int), stream);
    k_gemm <<<gblk, 256, 0, stream>>>(X, W, a, hb, s_src, s_tgt, ei, deg,
                                      N, nstripes, E, epb);
    k_alloc<<<(N + 255) / 256, 256, 0, stream>>>(deg, cur, cnt, N);
    k_fill <<<1024, 256, 0, stream>>>(ei, cur, csr_src, E);
    k_node <<<(N + 3) / 4, 256, 0, stream>>>(deg, cur, csr_src, s_src, s_tgt,
                                             hb, out, N);
}

// Round 2
// 167.136 us; speedup vs baseline: 1.2441x; 1.2441x over previous
//
#include <hip/hip_runtime.h>
#include <math.h>

#define ALPHA_LEAKY 0.2f
#define EPS_F 1e-10f
#define NBMAX 1024   // max buckets (N <= 65536; also lets (src,tloc) pack in 22 bits)

typedef __attribute__((ext_vector_type(8))) short short8;   // 8 bf16 (4 VGPRs)
typedef __attribute__((ext_vector_type(4))) float f32x4;    // MFMA C/D frag

__device__ __forceinline__ unsigned short bf16_rne(float f) {
    unsigned u = __float_as_uint(f);
    u += 0x7FFFu + ((u >> 16) & 1u);
    return (unsigned short)(u >> 16);
}

// MFMA GEMM + fused scores + fused per-block bucket histogram.
// One wave per 16-row stripe; W-frags built in-register from fp32 W.
// Tail: LDS histogram of bucket = tgt>>6 over this block's edge chunk,
// flushed as one coalesced row of histg[blockIdx][*]. No per-edge global
// atomics anywhere (lesson from r1: random 4B global RMW = ~60us/pass).
// C/D map: col = lane&15 (ml), row = (lane>>4)*4 + reg.
__global__ __launch_bounds__(256) void k_gemm(
    const float* __restrict__ X, const float* __restrict__ W,
    const float* __restrict__ a, unsigned short* __restrict__ hb,
    float* __restrict__ s_src, float* __restrict__ s_tgt,
    const int* __restrict__ ei, int* __restrict__ histg,
    int n, int nstripes, int nb, int E, int epb) {
    __shared__ int hist[NBMAX];
    for (int k = threadIdx.x; k < NBMAX; k += 256) hist[k] = 0;
    __syncthreads();

    const int lane = threadIdx.x & 63;
    const int ml = lane & 15, g = lane >> 4;

    // B-frags: frag(nt,kt): nn = nt*16 + ml, k = kt*32 + g*8, 8 elems.
    short8 bfr[4][4];
    #pragma unroll
    for (int nt = 0; nt < 4; ++nt)
        #pragma unroll
        for (int kt = 0; kt < 4; ++kt) {
            const float* wr = W + (nt * 16 + ml) * 128 + kt * 32 + g * 8;
            float4 w0 = *(const float4*)wr;
            float4 w1 = *(const float4*)(wr + 4);
            short8 bf;
            bf[0] = (short)bf16_rne(w0.x); bf[1] = (short)bf16_rne(w0.y);
            bf[2] = (short)bf16_rne(w0.z); bf[3] = (short)bf16_rne(w0.w);
            bf[4] = (short)bf16_rne(w1.x); bf[5] = (short)bf16_rne(w1.y);
            bf[6] = (short)bf16_rne(w1.z); bf[7] = (short)bf16_rne(w1.w);
            bfr[nt][kt] = bf;
        }
    float as[4], at[4];
    #pragma unroll
    for (int nt = 0; nt < 4; ++nt) {
        as[nt] = a[nt * 16 + ml];
        at[nt] = a[64 + nt * 16 + ml];
    }

    for (int stripe = blockIdx.x * 4 + (threadIdx.x >> 6); stripe < nstripes;
         stripe += gridDim.x * 4) {
        const int row0 = stripe * 16;
        const int rrow = min(row0 + ml, n - 1);
        const float* xr = X + (size_t)rrow * 128;
        f32x4 acc[4] = {{0.f,0.f,0.f,0.f},{0.f,0.f,0.f,0.f},
                        {0.f,0.f,0.f,0.f},{0.f,0.f,0.f,0.f}};
        #pragma unroll
        for (int kt = 0; kt < 4; ++kt) {
            float4 x0 = *(const float4*)(xr + kt * 32 + g * 8);
            float4 x1 = *(const float4*)(xr + kt * 32 + g * 8 + 4);
            short8 af;
            af[0] = (short)bf16_rne(x0.x); af[1] = (short)bf16_rne(x0.y);
            af[2] = (short)bf16_rne(x0.z); af[3] = (short)bf16_rne(x0.w);
            af[4] = (short)bf16_rne(x1.x); af[5] = (short)bf16_rne(x1.y);
            af[6] = (short)bf16_rne(x1.z); af[7] = (short)bf16_rne(x1.w);
            #pragma unroll
            for (int nt = 0; nt < 4; ++nt)
                acc[nt] = __builtin_amdgcn_mfma_f32_16x16x32_bf16(
                    af, bfr[nt][kt], acc[nt], 0, 0, 0);
        }
        #pragma unroll
        for (int reg = 0; reg < 4; ++reg) {
            int row = row0 + g * 4 + reg;
            float p = acc[0][reg] * as[0] + acc[1][reg] * as[1] +
                      acc[2][reg] * as[2] + acc[3][reg] * as[3];
            float q = acc[0][reg] * at[0] + acc[1][reg] * at[1] +
                      acc[2][reg] * at[2] + acc[3][reg] * at[3];
            #pragma unroll
            for (int off = 1; off < 16; off <<= 1) {
                p += __shfl_xor(p, off, 64);
                q += __shfl_xor(q, off, 64);
            }
            if (ml == 0 && row < n) { s_src[row] = p; s_tgt[row] = q; }
        }
        #pragma unroll
        for (int nt = 0; nt < 4; ++nt)
            #pragma unroll
            for (int reg = 0; reg < 4; ++reg) {
                int row = row0 + g * 4 + reg;
                if (row < n)
                    hb[(size_t)row * 64 + nt * 16 + ml] = bf16_rne(acc[nt][reg]);
            }
    }

    // bucket histogram of this block's edge chunk (LDS atomics only)
    {
        const int e0 = blockIdx.x * epb;
        const int e1 = min(e0 + epb, E);
        for (int e = e0 + (int)threadIdx.x; e < e1; e += 256)
            atomicAdd(&hist[ei[E + e] >> 6], 1);
    }
    __syncthreads();
    int* outp = histg + (size_t)blockIdx.x * nb;
    for (int k = threadIdx.x; k < nb; k += 256) outp[k] = hist[k];
}

// Fused column-scan + region allocation. One block per bucket:
// scan the R per-block counts (in block order -> deterministic within-bucket
// layout), then grab the bucket's base with ONE atomicAdd on a single
// counter (region order across buckets is irrelevant to correctness).
// Writes absolute offsets back into histg in place; breg[b] = (start, tot).
__global__ __launch_bounds__(256) void k_scan(
    int* __restrict__ histg, int2* __restrict__ breg,
    int* __restrict__ gcnt, int nb, int R) {
    __shared__ int wsum[4];
    __shared__ int bbase;
    const int b = blockIdx.x;
    const int t = threadIdx.x, lane = t & 63, w = t >> 6;
    int v[4], o[4];
    int carry = 0;
    #pragma unroll
    for (int c = 0; c < 4; ++c) {
        int row = c * 256 + t;
        v[c] = (row < R) ? histg[(size_t)row * nb + b] : 0;
    }
    #pragma unroll
    for (int c = 0; c < 4; ++c) {
        int incl = v[c];
        #pragma unroll
        for (int off = 1; off < 64; off <<= 1) {
            int x = __shfl_up(incl, off, 64);
            if (lane >= off) incl += x;
        }
        if (lane == 63) wsum[w] = incl;
        __syncthreads();
        int wb = 0;
        #pragma unroll
        for (int k = 0; k < 4; ++k) if (k < w) wb += wsum[k];
        int tot = wsum[0] + wsum[1] + wsum[2] + wsum[3];
        o[c] = carry + wb + incl - v[c];     // exclusive absolute-in-bucket
        carry += tot;
        __syncthreads();                      // wsum reused next chunk
    }
    if (t == 0) bbase = atomicAdd(gcnt, carry);
    __syncthreads();
    const int base = bbase;
    #pragma unroll
    for (int c = 0; c < 4; ++c) {
        int row = c * 256 + t;
        if (row < R) histg[(size_t)row * nb + b] = base + o[c];
    }
    if (t == 0) breg[b] = make_int2(base, carry);
}

// Place edges into bucket regions via LDS cursors seeded from histg.
// Packed entry: src | (tloc<<16)  (src < 65536 guaranteed by NBMAX cap).
// Writes per (block,bucket) are contiguous runs -> line-coalesced.
__global__ __launch_bounds__(256) void k_place(
    const int* __restrict__ ei, const int* __restrict__ histg,
    unsigned int* __restrict__ st, int nb, int E, int epb) {
    __shared__ int cur[NBMAX];
    const int t = threadIdx.x;
    const int* my = histg + (size_t)blockIdx.x * nb;
    for (int k = t; k < nb; k += 256) cur[k] = my[k];
    __syncthreads();
    const int e0 = blockIdx.x * epb, e1 = min(e0 + epb, E);
    for (int e = e0 + t; e < e1; e += 256) {
        int s  = ei[e];
        int tt = ei[E + e];
        int slot = atomicAdd(&cur[tt >> 6], 1);
        st[slot] = (unsigned)s | ((unsigned)(tt & 63) << 16);
    }
}

// Per-bucket local sort: LDS histogram of the 64 nodes -> deterministic
// base/deg; LDS-cursor placement writes csr_src into a contiguous region.
__global__ __launch_bounds__(256) void k_local(
    const unsigned int* __restrict__ st, const int2* __restrict__ breg,
    int* __restrict__ base, int* __restrict__ deg, int* __restrict__ csr_src,
    int n) {
    __shared__ int hist[64];
    __shared__ int nbase[64];
    const int b = blockIdx.x;
    const int n0 = b << 6;
    const int t = threadIdx.x;
    if (t < 64) hist[t] = 0;
    __syncthreads();
    const int2 reg = breg[b];
    const int s0 = reg.x, s1 = reg.x + reg.y;
    for (int i = s0 + t; i < s1; i += 256)
        atomicAdd(&hist[st[i] >> 16], 1);
    __syncthreads();
    if (t < 64) {
        int v = hist[t];
        int pre = v;
        #pragma unroll
        for (int off = 1; off < 64; off <<= 1) {
            int x = __shfl_up(pre, off, 64);
            if (t >= off) pre += x;
        }
        int bs = s0 + pre - v;       // exclusive
        nbase[t] = bs;
        if (n0 + t < n) { base[n0 + t] = bs; deg[n0 + t] = v; }
    }
    __syncthreads();
    if (t < 64) hist[t] = nbase[t];  // reuse as cursors
    __syncthreads();
    for (int i = s0 + t; i < s1; i += 256) {
        unsigned e = st[i];
        int slot = atomicAdd(&hist[e >> 16], 1);
        csr_src[slot] = (int)(e & 0xFFFFu);
    }
}

// per-node softmax + aggregation + ELU (one wave per node; lane = (g,r);
// 8 edges per step, each 8-lane group reads one 128 B bf16 row as uint4).
__device__ __forceinline__ void accum8(float acc[8], uint4 hv, float w) {
    unsigned u[4] = {hv.x, hv.y, hv.z, hv.w};
    #pragma unroll
    for (int i = 0; i < 4; ++i) {
        float lo = __uint_as_float(u[i] << 16);
        float hi = __uint_as_float(u[i] & 0xFFFF0000u);
        acc[2 * i]     = fmaf(w, lo, acc[2 * i]);
        acc[2 * i + 1] = fmaf(w, hi, acc[2 * i + 1]);
    }
}

__global__ __launch_bounds__(256) void k_node(
    const int* __restrict__ base, const int* __restrict__ deg,
    const int* __restrict__ csr_src, const float* __restrict__ s_src,
    const float* __restrict__ s_tgt, const unsigned short* __restrict__ hb,
    float* __restrict__ out, int n) {
    const int lane = threadIdx.x & 63;
    const int node = blockIdx.x * 4 + (threadIdx.x >> 6);
    if (node >= n) return;
    const int b = base[node];
    const int d = deg[node];
    const float st = s_tgt[node];
    const int g = lane >> 3, r = lane & 7;
    float acc[8] = {0.f, 0.f, 0.f, 0.f, 0.f, 0.f, 0.f, 0.f};

    if (d <= 64) {
        int src_l = 0; float w_l = 0.f, v = -INFINITY;
        if (lane < d) {
            src_l = csr_src[b + lane];
            float x = s_src[src_l] + st;
            v = (x > 0.f) ? x : ALPHA_LEAKY * x;
        }
        float m = v;
        #pragma unroll
        for (int off = 32; off > 0; off >>= 1) m = fmaxf(m, __shfl_xor(m, off, 64));
        float ex = (lane < d) ? expf(v - m) : 0.f;
        float sum = ex;
        #pragma unroll
        for (int off = 32; off > 0; off >>= 1) sum += __shfl_xor(sum, off, 64);
        w_l = ex * (1.f / (sum + EPS_F));
        for (int k = 0; k < d; k += 8) {
            int ke = k + g;
            int s   = __shfl(src_l, ke, 64);
            float w = __shfl(w_l,  ke, 64);
            uint4 hv = ((const uint4*)(hb + (size_t)s * 64))[r];
            accum8(acc, hv, w);
        }
    } else {
        float m = -INFINITY;
        for (int c = lane; c < d; c += 64) {
            float x = s_src[csr_src[b + c]] + st;
            x = (x > 0.f) ? x : ALPHA_LEAKY * x;
            m = fmaxf(m, x);
        }
        #pragma unroll
        for (int off = 32; off > 0; off >>= 1) m = fmaxf(m, __shfl_xor(m, off, 64));
        float sum = 0.f;
        for (int c = lane; c < d; c += 64) {
            float x = s_src[csr_src[b + c]] + st;
            x = (x > 0.f) ? x : ALPHA_LEAKY * x;
            sum += expf(x - m);
        }
        #pragma unroll
        for (int off = 32; off > 0; off >>= 1) sum += __shfl_xor(sum, off, 64);
        float inv = 1.f / (sum + EPS_F);
        for (int c0 = 0; c0 < d; c0 += 64) {
            int j = c0 + lane;
            int src_l = 0; float w_l = 0.f;
            if (j < d) {
                src_l = csr_src[b + j];
                float x = s_src[src_l] + st;
                x = (x > 0.f) ? x : ALPHA_LEAKY * x;
                w_l = expf(x - m) * inv;
            }
            int lim = min(64, d - c0);
            for (int k = 0; k < lim; k += 8) {
                int ke = k + g;
                int s   = __shfl(src_l, ke, 64);
                float w = __shfl(w_l,  ke, 64);
                uint4 hv = ((const uint4*)(hb + (size_t)s * 64))[r];
                accum8(acc, hv, w);
            }
        }
    }

    #pragma unroll
    for (int off = 8; off <= 32; off <<= 1) {
        #pragma unroll
        for (int j = 0; j < 8; ++j) acc[j] += __shfl_xor(acc[j], off, 64);
    }
    if (g == 0) {
        float4 o0, o1;
        o0.x = acc[0] > 0.f ? acc[0] : expf(acc[0]) - 1.f;
        o0.y = acc[1] > 0.f ? acc[1] : expf(acc[1]) - 1.f;
        o0.z = acc[2] > 0.f ? acc[2] : expf(acc[2]) - 1.f;
        o0.w = acc[3] > 0.f ? acc[3] : expf(acc[3]) - 1.f;
        o1.x = acc[4] > 0.f ? acc[4] : expf(acc[4]) - 1.f;
        o1.y = acc[5] > 0.f ? acc[5] : expf(acc[5]) - 1.f;
        o1.z = acc[6] > 0.f ? acc[6] : expf(acc[6]) - 1.f;
        o1.w = acc[7] > 0.f ? acc[7] : expf(acc[7]) - 1.f;
        float4* o4 = (float4*)out + (size_t)node * 16;
        o4[r * 2]     = o0;
        o4[r * 2 + 1] = o1;
    }
}

extern "C" void kernel_launch(void* const* d_in, const int* in_sizes, int n_in,
                              void* d_out, int out_size, void* d_ws, size_t ws_size,
                              hipStream_t stream) {
    const float* X  = (const float*)d_in[0];   // [N,128]
    const int*   ei = (const int*)d_in[1];     // [2,E]
    const float* W  = (const float*)d_in[2];   // [64,128]
    const float* a  = (const float*)d_in[3];   // [1,128]
    float* out = (float*)d_out;                // [N,64]

    const int N = in_sizes[0] / 128;
    const int E = in_sizes[1] / 2;
    const int nb = (N + 63) >> 6;              // buckets of 64 nodes (<=1024)
    const int nstripes = (N + 15) / 16;
    const int R = (nstripes + 3) / 4;          // gemm grid; == nb (64 rows/blk)
    const int epb = (E + R - 1) / R;           // edges per gemm/place block

    char* p = (char*)d_ws;
    unsigned short* hb = (unsigned short*)p; p += (size_t)N * 64 * sizeof(unsigned short);
    float* s_src  = (float*)p;  p += (size_t)N * sizeof(float);
    float* s_tgt  = (float*)p;  p += (size_t)N * sizeof(float);
    int*   deg    = (int*)p;    p += (size_t)N * sizeof(int);
    int*   base   = (int*)p;    p += (size_t)N * sizeof(int);
    int*   gcnt   = (int*)p;    p += 4 * sizeof(int);
    int*   histg  = (int*)p;    p += (size_t)R * nb * sizeof(int);
    int2*  breg   = (int2*)p;   p += (size_t)nb * sizeof(int2);
    int*   csr_src= (int*)p;    p += (size_t)E * sizeof(int);
    unsigned int* st = (unsigned int*)p;

    hipMemsetAsync(gcnt, 0, sizeof(int), stream);
    k_gemm <<<R, 256, 0, stream>>>(X, W, a, hb, s_src, s_tgt, ei, histg,
                                   N, nstripes, nb, E, epb);
    k_scan <<<nb, 256, 0, stream>>>(histg, breg, gcnt, nb, R);
    k_place<<<R, 256, 0, stream>>>(ei, histg, st, nb, E, epb);
    k_local<<<nb, 256, 0, stream>>>(st, breg, base, deg, csr_src, N);
    k_node <<<(N + 3) / 4, 256, 0, stream>>>(base, deg, csr_src, s_src, s_tgt,
                                             hb, out, N);
}